// Round 13
// baseline (67.493 us; speedup 1.0000x reference)
//
#include <hip/hip_runtime.h>
#include <hip/hip_bf16.h>

// MSTGCN head — fused bf16-MFMA implementation (round 13).
// cheb = [I,-I,I] (identity adjacency) => graph conv = per-(b,n) GEMM with
// te = theta0 - theta1 + theta2.
//
// Round-13 vs round-12 (barrier-phase-serialized: 11 barriers, single 24KB WB
// blocks any cross-phase prefetch; every pipe <30% busy):
//  - ALL 120 weight frags resident in LDS (120KB) + 6 wave-private 6KB tiles
//    = 156KB LDS, 1 block/CU (gfx950 has 160KB; 80KB static already ran in R8).
//  - ONE barrier total: stage 120 frags via global_load_lds (20/wave, 6 waves),
//    __syncthreads, then each wave runs the full chain barrier-free.
//  - dual-acc single-pass GEMMs (round-8 form): no __launch_bounds__ cap ->
//    ~190 VGPRs, no spill, fewer weight reads.
//  - block = 384 thr (6 waves x 4 pairs = 24 pairs), grid = ceil(16384/24)=683.
//    16384 % 4 == 0 -> tail waves are all-or-nothing; they exit after the
//    single barrier.

typedef __attribute__((ext_vector_type(8))) short bf16x8;
typedef __attribute__((ext_vector_type(4))) float f32x4;

typedef __attribute__((address_space(1))) const unsigned int gu32;
typedef __attribute__((address_space(3))) unsigned int lu32;

#define FR_W1   0     // 32 frags: ks(4)*8 + nt(8)   K=128,N=128 [te0|rw0T]
#define FR_TW0  32    // 24 frags: dt*8 + ks(2)*4 + nt(4)
#define FR_W2   56    // 16 frags: ks(2)*8 + nt(8)   K=64,N=128 [te1|rw1T]
#define FR_TW1  72    // 24 frags
#define FR_FW   96    // 24 frags: ks(24), N=16 (cols 12..15 zero)
#define N_FRAGS 120

__device__ __forceinline__ unsigned short f2bf(float f) {
    unsigned u = __builtin_bit_cast(unsigned, f);
    return (unsigned short)((u + 0x7FFFu + ((u >> 16) & 1u)) >> 16);
}

__device__ __forceinline__ unsigned short hcvt(float f) {
    union { __hip_bfloat16 h; unsigned short u; } cv;
    cv.h = __float2bfloat16(f);
    return cv.u;
}

// 16-lane (DPP row) all-reduce add, pure VALU.
template <int CTRL>
__device__ __forceinline__ float dpp_add(float v) {
    int t = __builtin_amdgcn_update_dpp(0, __builtin_bit_cast(int, v),
                                        CTRL, 0xf, 0xf, true);
    return v + __builtin_bit_cast(float, t);
}
__device__ __forceinline__ float red16(float v) {
    v = dpp_add<0xB1>(v);    // quad_perm xor1
    v = dpp_add<0x4E>(v);    // quad_perm xor2
    v = dpp_add<0x141>(v);   // row_half_mirror (xor4 effective)
    v = dpp_add<0x140>(v);   // row_mirror      (xor8 effective)
    return v;
}

__global__ void prep(const float* __restrict__ th0, const float* __restrict__ tw0,
                     const float* __restrict__ rw0, const float* __restrict__ th1,
                     const float* __restrict__ tw1, const float* __restrict__ rw1,
                     const float* __restrict__ fw,  short* __restrict__ wsb)
{
    int e = blockIdx.x * 256 + threadIdx.x;     // (frag, lane, i)
    if (e >= N_FRAGS * 512) return;
    int frag = e >> 9;
    int l    = (e >> 3) & 63;
    int i    = e & 7;
    int kif  = ((l >> 4) << 3) + i;             // k within 32-chunk
    int nif  = l & 15;
    float val = 0.f;
    if (frag < 32) {                                       // W1
        int ks = frag >> 3, nt = frag & 7;
        int k = ks * 32 + kif, n = nt * 16 + nif;
        if (n < 64) val = th0[k*64+n] - th0[8192 + k*64+n] + th0[16384 + k*64+n];
        else        val = rw0[(n - 64) * 128 + k];
    } else if (frag < 56) {                                // TW0
        int q = frag - 32; int dt = q >> 3, ks = (q >> 2) & 1, nt = q & 3;
        int c = ks * 32 + kif, o = nt * 16 + nif;
        val = tw0[o * 192 + c * 3 + dt];
    } else if (frag < 72) {                                // W2
        int q = frag - 56; int ks = q >> 3, nt = q & 7;
        int k = ks * 32 + kif, n = nt * 16 + nif;
        if (n < 64) val = th1[k*64+n] - th1[4096 + k*64+n] + th1[8192 + k*64+n];
        else        val = rw1[(n - 64) * 64 + k];
    } else if (frag < 96) {                                // TW1
        int q = frag - 72; int dt = q >> 3, ks = (q >> 2) & 1, nt = q & 3;
        int c = ks * 32 + kif, o = nt * 16 + nif;
        val = tw1[o * 192 + c * 3 + dt];
    } else {                                               // FW
        int ks = frag - 96; int k = ks * 32 + kif; int po = nif;
        val = (po < 12) ? fw[po * 768 + k] : 0.f;
    }
    wsb[e] = (short)f2bf(val);
}

// LDS layout:
//   [0 .. 36863]      : 6 per-wave 48x64 bf16 s/y tiles (6 KB each, swizzled)
//   [36864 .. 159743] : 120 KB weight buffer — ALL frags, slot = frag index
#define LDS_SY(w)  (LDS + (w) * 6144)
#define LDS_WB     (LDS + 36864)

__global__ __launch_bounds__(384, 1) void mstgcn_mfma(
    const float* __restrict__ x,   const short* __restrict__ wsb,
    const float* __restrict__ tb0, const float* __restrict__ rb0,
    const float* __restrict__ lg0, const float* __restrict__ lb0,
    const float* __restrict__ tb1, const float* __restrict__ rb1,
    const float* __restrict__ lg1, const float* __restrict__ lb1,
    const float* __restrict__ fb,  float* __restrict__ out)
{
    __shared__ __align__(16) char LDS[159744];

    const int lane = threadIdx.x & 63;
    const int wave = threadIdx.x >> 6;
    const int l15  = lane & 15;
    const int l4   = lane >> 4;
    const int pair0 = blockIdx.x * 24 + wave * 4;
    const bool alive = (pair0 < 16384);

    char* syB = LDS_SY(wave);
    char* WB  = LDS_WB;

    auto ldwb = [&](int f) -> bf16x8 {
        return *(const bf16x8*)(WB + f * 1024 + lane * 16);
    };

    // ============ stage ALL 120 frags once (20/wave, async to LDS) ==========
    #pragma unroll
    for (int i = 0; i < 20; ++i) {
        int f = wave * 20 + i;
        __builtin_amdgcn_global_load_lds(
            (gu32*)(wsb + f * 512 + lane * 8),
            (lu32*)(WB + f * 1024), 16, 0, 0);
    }

    // A-row decode + X prefetch -> aC (overlaps stage loads)
    int tA[3];
    bf16x8 aC[12];
    if (alive) {
        #pragma unroll
        for (int mt = 0; mt < 3; ++mt) {
            int r = mt * 16 + l15;
            int p = r / 12;
            tA[mt] = r - p * 12;
            long gb = ((long)(pair0 + p) * 12 + tA[mt]) * 128;
            #pragma unroll
            for (int ks = 0; ks < 4; ++ks) {
                const float* pp = x + gb + ks * 32 + l4 * 8;
                float v[8];
                *(float4*)(v)     = *(const float4*)(pp);
                *(float4*)(v + 4) = *(const float4*)(pp + 4);
                bf16x8 af;
                #pragma unroll
                for (int j = 0; j < 8; ++j) af[j] = (short)hcvt(v[j]);
                aC[ks * 3 + mt] = af;
            }
        }
    }
    __syncthreads();               // THE one barrier: all weights resident
    if (!alive) return;

    // ============ GEMM1: X @ [te0 | rw0T], dual acc, single pass ============
    f32x4 accS[3][4] = {}, accR[3][4] = {};
    #pragma unroll
    for (int ks = 0; ks < 4; ++ks) {
        #pragma unroll
        for (int nt = 0; nt < 4; ++nt) {
            bf16x8 b = ldwb(FR_W1 + ks * 8 + nt);
            #pragma unroll
            for (int mt = 0; mt < 3; ++mt)
                accS[mt][nt] = __builtin_amdgcn_mfma_f32_16x16x32_bf16(aC[ks * 3 + mt], b, accS[mt][nt], 0, 0, 0);
        }
        #pragma unroll
        for (int nt = 0; nt < 4; ++nt) {
            bf16x8 b = ldwb(FR_W1 + ks * 8 + 4 + nt);
            #pragma unroll
            for (int mt = 0; mt < 3; ++mt)
                accR[mt][nt] = __builtin_amdgcn_mfma_f32_16x16x32_bf16(aC[ks * 3 + mt], b, accR[mt][nt], 0, 0, 0);
        }
    }
    // epilogue: s = relu(accS) -> own tile (swizzled bf16); wave-private
    #pragma unroll
    for (int mt = 0; mt < 3; ++mt)
        #pragma unroll
        for (int j = 0; j < 4; ++j) {
            int row = mt * 16 + l4 * 4 + j;
            int sw  = (row & 7) << 4;
            #pragma unroll
            for (int nt = 0; nt < 4; ++nt) {
                int col = nt * 16 + l15;
                *(short*)(syB + row * 128 + ((col * 2) ^ sw)) =
                    (short)hcvt(fmaxf(accS[mt][nt][j], 0.f));
            }
        }

    // ============ tconv0 (3 shifted GEMMs) += accR ============
    #pragma unroll
    for (int dt = 0; dt < 3; ++dt) {
        #pragma unroll
        for (int ks = 0; ks < 2; ++ks) {
            bf16x8 a[3];
            #pragma unroll
            for (int mt = 0; mt < 3; ++mt) {
                int ts    = tA[mt] + dt - 1;
                bool ok   = (ts >= 0) && (ts < 12);
                int srow  = ok ? (mt * 16 + l15 + dt - 1) : (mt * 16 + l15);
                int kb    = (ks * 32 + l4 * 8) * 2;
                bf16x8 av = *(const bf16x8*)(syB + srow * 128 + (kb ^ ((srow & 7) << 4)));
                a[mt] = ok ? av : (bf16x8)(short)0;
            }
            #pragma unroll
            for (int nt = 0; nt < 4; ++nt) {
                bf16x8 b = ldwb(FR_TW0 + dt * 8 + ks * 4 + nt);
                #pragma unroll
                for (int mt = 0; mt < 3; ++mt)
                    accR[mt][nt] = __builtin_amdgcn_mfma_f32_16x16x32_bf16(a[mt], b, accR[mt][nt], 0, 0, 0);
            }
        }
    }

    // ============ bias + relu + LN0 -> y1 into own tile ============
    {
        float bv[4], lgv[4], lbv[4];
        #pragma unroll
        for (int nt = 0; nt < 4; ++nt) {
            int col = nt * 16 + l15;
            bv[nt]  = rb0[col] + tb0[col];
            lgv[nt] = lg0[col];
            lbv[nt] = lb0[col];
        }
        #pragma unroll
        for (int mt = 0; mt < 3; ++mt)
            #pragma unroll
            for (int j = 0; j < 4; ++j) {
                float v[4], sm = 0.f, sq = 0.f;
                #pragma unroll
                for (int nt = 0; nt < 4; ++nt) {
                    v[nt] = fmaxf(accR[mt][nt][j] + bv[nt], 0.f);
                    sm += v[nt]; sq += v[nt] * v[nt];
                }
                sm = red16(sm);
                sq = red16(sq);
                float mu = sm * 0.015625f;
                float is = rsqrtf(sq * 0.015625f - mu * mu + 1e-5f);
                int row = mt * 16 + l4 * 4 + j;
                int sw  = (row & 7) << 4;
                #pragma unroll
                for (int nt = 0; nt < 4; ++nt) {
                    int col = nt * 16 + l15;
                    *(short*)(syB + row * 128 + ((col * 2) ^ sw)) =
                        (short)hcvt((v[nt] - mu) * is * lgv[nt] + lbv[nt]);
                }
            }
    }

    // cache y1 A-frags (wave-private tile; same-wave RAW is issue-ordered)
    bf16x8 aC2[6];
    #pragma unroll
    for (int ks = 0; ks < 2; ++ks)
        #pragma unroll
        for (int mt = 0; mt < 3; ++mt) {
            int row = mt * 16 + l15;
            int kb  = (ks * 32 + l4 * 8) * 2;
            aC2[ks * 3 + mt] = *(const bf16x8*)(syB + row * 128 + (kb ^ ((row & 7) << 4)));
        }

    // ============ GEMM2: y1 @ [te1 | rw1T], dual acc ============
    #pragma unroll
    for (int mt = 0; mt < 3; ++mt)
        #pragma unroll
        for (int nt = 0; nt < 4; ++nt) { accS[mt][nt] = (f32x4)0.f; accR[mt][nt] = (f32x4)0.f; }
    #pragma unroll
    for (int ks = 0; ks < 2; ++ks) {
        #pragma unroll
        for (int nt = 0; nt < 4; ++nt) {
            bf16x8 b = ldwb(FR_W2 + ks * 8 + nt);
            #pragma unroll
            for (int mt = 0; mt < 3; ++mt)
                accS[mt][nt] = __builtin_amdgcn_mfma_f32_16x16x32_bf16(aC2[ks * 3 + mt], b, accS[mt][nt], 0, 0, 0);
        }
        #pragma unroll
        for (int nt = 0; nt < 4; ++nt) {
            bf16x8 b = ldwb(FR_W2 + ks * 8 + 4 + nt);
            #pragma unroll
            for (int mt = 0; mt < 3; ++mt)
                accR[mt][nt] = __builtin_amdgcn_mfma_f32_16x16x32_bf16(aC2[ks * 3 + mt], b, accR[mt][nt], 0, 0, 0);
        }
    }
    // s1 = relu(accS) overwrites y1 tile (y1 safe in aC2)
    #pragma unroll
    for (int mt = 0; mt < 3; ++mt)
        #pragma unroll
        for (int j = 0; j < 4; ++j) {
            int row = mt * 16 + l4 * 4 + j;
            int sw  = (row & 7) << 4;
            #pragma unroll
            for (int nt = 0; nt < 4; ++nt) {
                int col = nt * 16 + l15;
                *(short*)(syB + row * 128 + ((col * 2) ^ sw)) =
                    (short)hcvt(fmaxf(accS[mt][nt][j], 0.f));
            }
        }

    // ============ tconv1 += accR ============
    #pragma unroll
    for (int dt = 0; dt < 3; ++dt) {
        #pragma unroll
        for (int ks = 0; ks < 2; ++ks) {
            bf16x8 a[3];
            #pragma unroll
            for (int mt = 0; mt < 3; ++mt) {
                int ts    = tA[mt] + dt - 1;
                bool ok   = (ts >= 0) && (ts < 12);
                int srow  = ok ? (mt * 16 + l15 + dt - 1) : (mt * 16 + l15);
                int kb    = (ks * 32 + l4 * 8) * 2;
                bf16x8 av = *(const bf16x8*)(syB + srow * 128 + (kb ^ ((srow & 7) << 4)));
                a[mt] = ok ? av : (bf16x8)(short)0;
            }
            #pragma unroll
            for (int nt = 0; nt < 4; ++nt) {
                bf16x8 b = ldwb(FR_TW1 + dt * 8 + ks * 4 + nt);
                #pragma unroll
                for (int mt = 0; mt < 3; ++mt)
                    accR[mt][nt] = __builtin_amdgcn_mfma_f32_16x16x32_bf16(a[mt], b, accR[mt][nt], 0, 0, 0);
            }
        }
    }

    // ============ bias + relu + LN1 -> y2 back into own tile ============
    {
        float bv[4], lgv[4], lbv[4];
        #pragma unroll
        for (int nt = 0; nt < 4; ++nt) {
            int col = nt * 16 + l15;
            bv[nt]  = rb1[col] + tb1[col];
            lgv[nt] = lg1[col];
            lbv[nt] = lb1[col];
        }
        #pragma unroll
        for (int mt = 0; mt < 3; ++mt)
            #pragma unroll
            for (int j = 0; j < 4; ++j) {
                float v[4], sm = 0.f, sq = 0.f;
                #pragma unroll
                for (int nt = 0; nt < 4; ++nt) {
                    v[nt] = fmaxf(accR[mt][nt][j] + bv[nt], 0.f);
                    sm += v[nt]; sq += v[nt] * v[nt];
                }
                sm = red16(sm);
                sq = red16(sq);
                float mu = sm * 0.015625f;
                float is = rsqrtf(sq * 0.015625f - mu * mu + 1e-5f);
                int row = mt * 16 + l4 * 4 + j;
                int sw  = (row & 7) << 4;
                #pragma unroll
                for (int nt = 0; nt < 4; ++nt) {
                    int col = nt * 16 + l15;
                    *(short*)(syB + row * 128 + ((col * 2) ^ sw)) =
                        (short)hcvt((v[nt] - mu) * is * lgv[nt] + lbv[nt]);
                }
            }
    }

    // ============ final: per-wave, A-row = pair (rows >=4 clamped) ============
    {
        f32x4 acc0 = (f32x4)0.f, acc1 = (f32x4)0.f;
        int p   = (l15 < 4) ? l15 : 0;
        #pragma unroll
        for (int ks = 0; ks < 24; ks += 2) {
            {   // even ks
                int t = ks >> 1, f0 = l4 * 8;
                int row = p * 12 + t;
                bf16x8 a = *(const bf16x8*)(syB + row * 128 + ((f0 * 2) ^ ((row & 7) << 4)));
                acc0 = __builtin_amdgcn_mfma_f32_16x16x32_bf16(a, ldwb(FR_FW + ks), acc0, 0, 0, 0);
            }
            {   // odd ks
                int t = ks >> 1, f0 = 32 + l4 * 8;
                int row = p * 12 + t;
                bf16x8 a = *(const bf16x8*)(syB + row * 128 + ((f0 * 2) ^ ((row & 7) << 4)));
                acc1 = __builtin_amdgcn_mfma_f32_16x16x32_bf16(a, ldwb(FR_FW + ks + 1), acc1, 0, 0, 0);
            }
        }
        if (l4 == 0 && l15 < 12) {
            float fbv = fb[l15];
            #pragma unroll
            for (int j = 0; j < 4; ++j)
                out[(long)(pair0 + j) * 12 + l15] = acc0[j] + acc1[j] + fbv;
        }
    }
}

extern "C" void kernel_launch(void* const* d_in, const int* in_sizes, int n_in,
                              void* d_out, int out_size, void* d_ws, size_t ws_size,
                              hipStream_t stream)
{
    (void)in_sizes; (void)n_in; (void)out_size; (void)ws_size;
    const float* x   = (const float*)d_in[0];
    const float* th0 = (const float*)d_in[1];
    const float* tw0 = (const float*)d_in[2];
    const float* tb0 = (const float*)d_in[3];
    const float* rw0 = (const float*)d_in[4];
    const float* rb0 = (const float*)d_in[5];
    const float* lg0 = (const float*)d_in[6];
    const float* lb0 = (const float*)d_in[7];
    const float* th1 = (const float*)d_in[8];
    const float* tw1 = (const float*)d_in[9];
    const float* tb1 = (const float*)d_in[10];
    const float* rw1 = (const float*)d_in[11];
    const float* rb1 = (const float*)d_in[12];
    const float* lg1 = (const float*)d_in[13];
    const float* lb1 = (const float*)d_in[14];
    const float* fw  = (const float*)d_in[15];
    const float* fb  = (const float*)d_in[16];
    float* out = (float*)d_out;
    short* wsb = (short*)d_ws;

    prep<<<240, 256, 0, stream>>>(th0, tw0, rw0, th1, tw1, rw1, fw, wsb);
    mstgcn_mfma<<<683, 384, 0, stream>>>(x, wsb, tb0, rb0, lg0, lb0,
                                         tb1, rb1, lg1, lb1, fb, out);
}

// Round 14
// 50.270 us; speedup vs baseline: 1.3426x; 1.3426x over previous
//
#include <hip/hip_runtime.h>
#include <hip/hip_bf16.h>

// MSTGCN head — fused bf16-MFMA implementation (round 14).
// cheb = [I,-I,I] (identity adjacency) => graph conv = per-(b,n) GEMM with
// te = theta0 - theta1 + theta2.
//
// Round-14 vs round-12/13: T14 issue-early/write-late weight staging.
// R13 refuted "barriers are the cost" (6 waves/CU, 1 barrier: WORSE). R12's
// remaining stall: 11 phases each expose full stage latency (issue right
// before vmcnt drain). Now each phase's fragments are loaded into REGISTERS
// during the PREVIOUS phase's compute, and ds_written after the done-reading
// barrier -> stage latency fully hidden.
//  - dual-acc single-pass GEMMs at __launch_bounds__(256,2): no 84/84 split,
//    96 acc + ~110 arch fits 256, removes W1R phase and y1-preservation issue.
//  - 5 phases {W1,TW0,W2,TW1,FW}, 9 barriers, WB 32KB + tiles 24KB = 56KB
//    -> 2 blocks/CU (8 waves).
//  - X loaded inline in GEMM1 (no aC cache), DPP LN kept.

typedef __attribute__((ext_vector_type(8))) short bf16x8;
typedef __attribute__((ext_vector_type(4))) float f32x4;

#define FR_W1   0     // 32 frags: ks(4)*8 + {nt | 4+nt}   [te0|rw0T]
#define FR_TW0  32    // 24 frags: dt*8 + ks(2)*4 + nt(4)
#define FR_W2   56    // 16 frags: ks(2)*8 + {nt | 4+nt}   [te1|rw1T]
#define FR_TW1  72    // 24 frags
#define FR_FW   96    // 24 frags: ks(24), N=16 (cols 12..15 zero)
#define N_FRAGS 120

__device__ __forceinline__ unsigned short f2bf(float f) {
    unsigned u = __builtin_bit_cast(unsigned, f);
    return (unsigned short)((u + 0x7FFFu + ((u >> 16) & 1u)) >> 16);
}

__device__ __forceinline__ unsigned short hcvt(float f) {
    union { __hip_bfloat16 h; unsigned short u; } cv;
    cv.h = __float2bfloat16(f);
    return cv.u;
}

// 16-lane (DPP row) all-reduce add, pure VALU.
template <int CTRL>
__device__ __forceinline__ float dpp_add(float v) {
    int t = __builtin_amdgcn_update_dpp(0, __builtin_bit_cast(int, v),
                                        CTRL, 0xf, 0xf, true);
    return v + __builtin_bit_cast(float, t);
}
__device__ __forceinline__ float red16(float v) {
    v = dpp_add<0xB1>(v);    // quad_perm xor1
    v = dpp_add<0x4E>(v);    // quad_perm xor2
    v = dpp_add<0x141>(v);   // row_half_mirror (xor4 effective)
    v = dpp_add<0x140>(v);   // row_mirror      (xor8 effective)
    return v;
}

__global__ void prep(const float* __restrict__ th0, const float* __restrict__ tw0,
                     const float* __restrict__ rw0, const float* __restrict__ th1,
                     const float* __restrict__ tw1, const float* __restrict__ rw1,
                     const float* __restrict__ fw,  short* __restrict__ wsb)
{
    int e = blockIdx.x * 256 + threadIdx.x;     // (frag, lane, i)
    if (e >= N_FRAGS * 512) return;
    int frag = e >> 9;
    int l    = (e >> 3) & 63;
    int i    = e & 7;
    int kif  = ((l >> 4) << 3) + i;             // k within 32-chunk
    int nif  = l & 15;
    float val = 0.f;
    if (frag < 32) {                                       // W1
        int ks = frag >> 3, nt = frag & 7;
        int k = ks * 32 + kif, n = nt * 16 + nif;
        if (n < 64) val = th0[k*64+n] - th0[8192 + k*64+n] + th0[16384 + k*64+n];
        else        val = rw0[(n - 64) * 128 + k];
    } else if (frag < 56) {                                // TW0
        int q = frag - 32; int dt = q >> 3, ks = (q >> 2) & 1, nt = q & 3;
        int c = ks * 32 + kif, o = nt * 16 + nif;
        val = tw0[o * 192 + c * 3 + dt];
    } else if (frag < 72) {                                // W2
        int q = frag - 56; int ks = q >> 3, nt = q & 7;
        int k = ks * 32 + kif, n = nt * 16 + nif;
        if (n < 64) val = th1[k*64+n] - th1[4096 + k*64+n] + th1[8192 + k*64+n];
        else        val = rw1[(n - 64) * 64 + k];
    } else if (frag < 96) {                                // TW1
        int q = frag - 72; int dt = q >> 3, ks = (q >> 2) & 1, nt = q & 3;
        int c = ks * 32 + kif, o = nt * 16 + nif;
        val = tw1[o * 192 + c * 3 + dt];
    } else {                                               // FW
        int ks = frag - 96; int k = ks * 32 + kif; int po = nif;
        val = (po < 12) ? fw[po * 768 + k] : 0.f;
    }
    wsb[e] = (short)f2bf(val);
}

// LDS layout:
//   [0 .. 24575]   : 4 per-wave 48x64 bf16 s/y tiles (6 KB each, XOR-swizzled)
//   [24576..57343] : 32 KB weight buffer (one phase at a time, slots 0..31)
#define LDS_SY(w)  (LDS + (w) * 6144)
#define LDS_WB     (LDS + 24576)

__global__ __launch_bounds__(256, 2) void mstgcn_mfma(
    const float* __restrict__ x,   const short* __restrict__ wsb,
    const float* __restrict__ tb0, const float* __restrict__ rb0,
    const float* __restrict__ lg0, const float* __restrict__ lb0,
    const float* __restrict__ tb1, const float* __restrict__ rb1,
    const float* __restrict__ lg1, const float* __restrict__ lb1,
    const float* __restrict__ fb,  float* __restrict__ out)
{
    __shared__ __align__(16) char LDS[57344];

    const int lane = threadIdx.x & 63;
    const int wave = threadIdx.x >> 6;
    const int l15  = lane & 15;
    const int l4   = lane >> 4;
    const int pair0 = blockIdx.x * 16 + wave * 4;

    char* syB = LDS_SY(wave);
    char* WB  = LDS_WB;

    auto ldwb = [&](int slot) -> bf16x8 {
        return *(const bf16x8*)(WB + slot * 1024 + lane * 16);
    };
    auto gld = [&](int fg) -> bf16x8 {          // global frag load -> regs
        return *(const bf16x8*)(wsb + fg * 512 + lane * 8);
    };
    auto dsw = [&](int slot, bf16x8 v) {        // regs -> WB slot
        *(bf16x8*)(WB + slot * 1024 + lane * 16) = v;
    };

    // A-row decode (rows 0..47 within wave; row -> (pair, t))
    int tA[3];
    long gbase[3];
    #pragma unroll
    for (int mt = 0; mt < 3; ++mt) {
        int r = mt * 16 + l15;
        int p = r / 12;
        tA[mt]   = r - p * 12;
        gbase[mt] = ((long)(pair0 + p) * 12 + tA[mt]) * 128;
    }

    bf16x8 stg[8];

    // ============ prologue: W1 (8 frags/wave) -> WB; issue TW0 early ========
    #pragma unroll
    for (int i = 0; i < 8; ++i) stg[i] = gld(wave * 8 + i);
    #pragma unroll
    for (int i = 0; i < 8; ++i) dsw(wave * 8 + i, stg[i]);
    #pragma unroll
    for (int i = 0; i < 6; ++i) stg[i] = gld(FR_TW0 + wave * 6 + i);  // TW0 in flight
    __syncthreads();                                   // B0: W1 resident

    // ============ GEMM1: X @ [te0 | rw0T], dual acc, X inline ============
    f32x4 accS[3][4] = {}, accR[3][4] = {};
    #pragma unroll
    for (int ks = 0; ks < 4; ++ks) {
        bf16x8 a[3];
        #pragma unroll
        for (int mt = 0; mt < 3; ++mt) {
            const float* pp = x + gbase[mt] + ks * 32 + l4 * 8;
            float v[8];
            *(float4*)(v)     = *(const float4*)(pp);
            *(float4*)(v + 4) = *(const float4*)(pp + 4);
            bf16x8 af;
            #pragma unroll
            for (int j = 0; j < 8; ++j) af[j] = (short)hcvt(v[j]);
            a[mt] = af;
        }
        #pragma unroll
        for (int nt = 0; nt < 4; ++nt) {
            bf16x8 b = ldwb(ks * 8 + nt);
            #pragma unroll
            for (int mt = 0; mt < 3; ++mt)
                accS[mt][nt] = __builtin_amdgcn_mfma_f32_16x16x32_bf16(a[mt], b, accS[mt][nt], 0, 0, 0);
        }
        #pragma unroll
        for (int nt = 0; nt < 4; ++nt) {
            bf16x8 b = ldwb(ks * 8 + 4 + nt);
            #pragma unroll
            for (int mt = 0; mt < 3; ++mt)
                accR[mt][nt] = __builtin_amdgcn_mfma_f32_16x16x32_bf16(a[mt], b, accR[mt][nt], 0, 0, 0);
        }
    }
    // epilogue: s = relu(accS) -> own tile (swizzled bf16)
    #pragma unroll
    for (int mt = 0; mt < 3; ++mt)
        #pragma unroll
        for (int j = 0; j < 4; ++j) {
            int row = mt * 16 + l4 * 4 + j;
            int sw  = (row & 7) << 4;
            #pragma unroll
            for (int nt = 0; nt < 4; ++nt) {
                int col = nt * 16 + l15;
                *(short*)(syB + row * 128 + ((col * 2) ^ sw)) =
                    (short)hcvt(fmaxf(accS[mt][nt][j], 0.f));
            }
        }
    __syncthreads();                                   // A1: done reading W1

    #pragma unroll
    for (int i = 0; i < 6; ++i) dsw(wave * 6 + i, stg[i]);            // TW0 -> WB
    #pragma unroll
    for (int i = 0; i < 4; ++i) stg[i] = gld(FR_W2 + wave * 4 + i);   // W2 in flight
    __syncthreads();                                   // B1: TW0 resident

    // ============ tconv0 (3 shifted GEMMs) += accR ============
    #pragma unroll
    for (int dt = 0; dt < 3; ++dt) {
        #pragma unroll
        for (int ks = 0; ks < 2; ++ks) {
            bf16x8 a[3];
            #pragma unroll
            for (int mt = 0; mt < 3; ++mt) {
                int ts    = tA[mt] + dt - 1;
                bool ok   = (ts >= 0) && (ts < 12);
                int srow  = ok ? (mt * 16 + l15 + dt - 1) : (mt * 16 + l15);
                int kb    = (ks * 32 + l4 * 8) * 2;
                bf16x8 av = *(const bf16x8*)(syB + srow * 128 + (kb ^ ((srow & 7) << 4)));
                a[mt] = ok ? av : (bf16x8)(short)0;
            }
            #pragma unroll
            for (int nt = 0; nt < 4; ++nt) {
                bf16x8 b = ldwb(dt * 8 + ks * 4 + nt);
                #pragma unroll
                for (int mt = 0; mt < 3; ++mt)
                    accR[mt][nt] = __builtin_amdgcn_mfma_f32_16x16x32_bf16(a[mt], b, accR[mt][nt], 0, 0, 0);
            }
        }
    }
    __syncthreads();                                   // A2: done reading TW0

    #pragma unroll
    for (int i = 0; i < 4; ++i) dsw(wave * 4 + i, stg[i]);            // W2 -> WB
    #pragma unroll
    for (int i = 0; i < 6; ++i) stg[i] = gld(FR_TW1 + wave * 6 + i);  // TW1 in flight

    // ============ bias + relu + LN0 -> y1 into own tile (DPP) ============
    {
        float bv[4], lgv[4], lbv[4];
        #pragma unroll
        for (int nt = 0; nt < 4; ++nt) {
            int col = nt * 16 + l15;
            bv[nt]  = rb0[col] + tb0[col];
            lgv[nt] = lg0[col];
            lbv[nt] = lb0[col];
        }
        #pragma unroll
        for (int mt = 0; mt < 3; ++mt)
            #pragma unroll
            for (int j = 0; j < 4; ++j) {
                float v[4], sm = 0.f, sq = 0.f;
                #pragma unroll
                for (int nt = 0; nt < 4; ++nt) {
                    v[nt] = fmaxf(accR[mt][nt][j] + bv[nt], 0.f);
                    sm += v[nt]; sq += v[nt] * v[nt];
                }
                sm = red16(sm);
                sq = red16(sq);
                float mu = sm * 0.015625f;
                float is = rsqrtf(sq * 0.015625f - mu * mu + 1e-5f);
                int row = mt * 16 + l4 * 4 + j;
                int sw  = (row & 7) << 4;
                #pragma unroll
                for (int nt = 0; nt < 4; ++nt) {
                    int col = nt * 16 + l15;
                    *(short*)(syB + row * 128 + ((col * 2) ^ sw)) =
                        (short)hcvt((v[nt] - mu) * is * lgv[nt] + lbv[nt]);
                }
            }
    }
    __syncthreads();                                   // B2: W2 resident

    // ============ GEMM2: y1 @ [te1 | rw1T], dual acc, y1 inline ============
    #pragma unroll
    for (int mt = 0; mt < 3; ++mt)
        #pragma unroll
        for (int nt = 0; nt < 4; ++nt) { accS[mt][nt] = (f32x4)0.f; accR[mt][nt] = (f32x4)0.f; }
    #pragma unroll
    for (int ks = 0; ks < 2; ++ks) {
        bf16x8 a[3];
        #pragma unroll
        for (int mt = 0; mt < 3; ++mt) {
            int row = mt * 16 + l15;
            int kb  = (ks * 32 + l4 * 8) * 2;
            a[mt] = *(const bf16x8*)(syB + row * 128 + (kb ^ ((row & 7) << 4)));
        }
        #pragma unroll
        for (int nt = 0; nt < 4; ++nt) {
            bf16x8 b = ldwb(ks * 8 + nt);
            #pragma unroll
            for (int mt = 0; mt < 3; ++mt)
                accS[mt][nt] = __builtin_amdgcn_mfma_f32_16x16x32_bf16(a[mt], b, accS[mt][nt], 0, 0, 0);
        }
        #pragma unroll
        for (int nt = 0; nt < 4; ++nt) {
            bf16x8 b = ldwb(ks * 8 + 4 + nt);
            #pragma unroll
            for (int mt = 0; mt < 3; ++mt)
                accR[mt][nt] = __builtin_amdgcn_mfma_f32_16x16x32_bf16(a[mt], b, accR[mt][nt], 0, 0, 0);
        }
    }
    // s1 = relu(accS) overwrites y1 tile (y1 dead after GEMM2)
    #pragma unroll
    for (int mt = 0; mt < 3; ++mt)
        #pragma unroll
        for (int j = 0; j < 4; ++j) {
            int row = mt * 16 + l4 * 4 + j;
            int sw  = (row & 7) << 4;
            #pragma unroll
            for (int nt = 0; nt < 4; ++nt) {
                int col = nt * 16 + l15;
                *(short*)(syB + row * 128 + ((col * 2) ^ sw)) =
                    (short)hcvt(fmaxf(accS[mt][nt][j], 0.f));
            }
        }
    __syncthreads();                                   // A3: done reading W2

    #pragma unroll
    for (int i = 0; i < 6; ++i) dsw(wave * 6 + i, stg[i]);            // TW1 -> WB
    #pragma unroll
    for (int i = 0; i < 6; ++i) stg[i] = gld(FR_FW + wave * 6 + i);   // FW in flight
    __syncthreads();                                   // B3: TW1 resident

    // ============ tconv1 += accR ============
    #pragma unroll
    for (int dt = 0; dt < 3; ++dt) {
        #pragma unroll
        for (int ks = 0; ks < 2; ++ks) {
            bf16x8 a[3];
            #pragma unroll
            for (int mt = 0; mt < 3; ++mt) {
                int ts    = tA[mt] + dt - 1;
                bool ok   = (ts >= 0) && (ts < 12);
                int srow  = ok ? (mt * 16 + l15 + dt - 1) : (mt * 16 + l15);
                int kb    = (ks * 32 + l4 * 8) * 2;
                bf16x8 av = *(const bf16x8*)(syB + srow * 128 + (kb ^ ((srow & 7) << 4)));
                a[mt] = ok ? av : (bf16x8)(short)0;
            }
            #pragma unroll
            for (int nt = 0; nt < 4; ++nt) {
                bf16x8 b = ldwb(dt * 8 + ks * 4 + nt);
                #pragma unroll
                for (int mt = 0; mt < 3; ++mt)
                    accR[mt][nt] = __builtin_amdgcn_mfma_f32_16x16x32_bf16(a[mt], b, accR[mt][nt], 0, 0, 0);
            }
        }
    }

    // ============ bias + relu + LN1 -> y2 back into own tile (DPP) ==========
    {
        float bv[4], lgv[4], lbv[4];
        #pragma unroll
        for (int nt = 0; nt < 4; ++nt) {
            int col = nt * 16 + l15;
            bv[nt]  = rb1[col] + tb1[col];
            lgv[nt] = lg1[col];
            lbv[nt] = lb1[col];
        }
        #pragma unroll
        for (int mt = 0; mt < 3; ++mt)
            #pragma unroll
            for (int j = 0; j < 4; ++j) {
                float v[4], sm = 0.f, sq = 0.f;
                #pragma unroll
                for (int nt = 0; nt < 4; ++nt) {
                    v[nt] = fmaxf(accR[mt][nt][j] + bv[nt], 0.f);
                    sm += v[nt]; sq += v[nt] * v[nt];
                }
                sm = red16(sm);
                sq = red16(sq);
                float mu = sm * 0.015625f;
                float is = rsqrtf(sq * 0.015625f - mu * mu + 1e-5f);
                int row = mt * 16 + l4 * 4 + j;
                int sw  = (row & 7) << 4;
                #pragma unroll
                for (int nt = 0; nt < 4; ++nt) {
                    int col = nt * 16 + l15;
                    *(short*)(syB + row * 128 + ((col * 2) ^ sw)) =
                        (short)hcvt((v[nt] - mu) * is * lgv[nt] + lbv[nt]);
                }
            }
    }
    __syncthreads();                                   // A4: done reading TW1

    #pragma unroll
    for (int i = 0; i < 6; ++i) dsw(wave * 6 + i, stg[i]);            // FW -> WB
    __syncthreads();                                   // B4: FW resident

    // ============ final: per-wave, A-row = pair (rows >=4 clamped) ============
    {
        f32x4 acc0 = (f32x4)0.f, acc1 = (f32x4)0.f;
        int p   = (l15 < 4) ? l15 : 0;
        #pragma unroll
        for (int ks = 0; ks < 24; ks += 2) {
            {   // even ks
                int t = ks >> 1, f0 = l4 * 8;
                int row = p * 12 + t;
                bf16x8 a = *(const bf16x8*)(syB + row * 128 + ((f0 * 2) ^ ((row & 7) << 4)));
                acc0 = __builtin_amdgcn_mfma_f32_16x16x32_bf16(a, ldwb(ks), acc0, 0, 0, 0);
            }
            {   // odd ks
                int t = ks >> 1, f0 = 32 + l4 * 8;
                int row = p * 12 + t;
                bf16x8 a = *(const bf16x8*)(syB + row * 128 + ((f0 * 2) ^ ((row & 7) << 4)));
                acc1 = __builtin_amdgcn_mfma_f32_16x16x32_bf16(a, ldwb(ks + 1), acc1, 0, 0, 0);
            }
        }
        if (l4 == 0 && l15 < 12) {
            float fbv = fb[l15];
            #pragma unroll
            for (int j = 0; j < 4; ++j)
                out[(long)(pair0 + j) * 12 + l15] = acc0[j] + acc1[j] + fbv;
        }
    }
}

extern "C" void kernel_launch(void* const* d_in, const int* in_sizes, int n_in,
                              void* d_out, int out_size, void* d_ws, size_t ws_size,
                              hipStream_t stream)
{
    (void)in_sizes; (void)n_in; (void)out_size; (void)ws_size;
    const float* x   = (const float*)d_in[0];
    const float* th0 = (const float*)d_in[1];
    const float* tw0 = (const float*)d_in[2];
    const float* tb0 = (const float*)d_in[3];
    const float* rw0 = (const float*)d_in[4];
    const float* rb0 = (const float*)d_in[5];
    const float* lg0 = (const float*)d_in[6];
    const float* lb0 = (const float*)d_in[7];
    const float* th1 = (const float*)d_in[8];
    const float* tw1 = (const float*)d_in[9];
    const float* tb1 = (const float*)d_in[10];
    const float* rw1 = (const float*)d_in[11];
    const float* rb1 = (const float*)d_in[12];
    const float* lg1 = (const float*)d_in[13];
    const float* lb1 = (const float*)d_in[14];
    const float* fw  = (const float*)d_in[15];
    const float* fb  = (const float*)d_in[16];
    float* out = (float*)d_out;
    short* wsb = (short*)d_ws;

    prep<<<240, 256, 0, stream>>>(th0, tw0, rw0, th1, tw1, rw1, fw, wsb);
    mstgcn_mfma<<<1024, 256, 0, stream>>>(x, wsb, tb0, rb0, lg0, lb0,
                                          tb1, rb1, lg1, lb1, fb, out);
}